// Round 1
// baseline (141.449 us; speedup 1.0000x reference)
//
#include <hip/hip_runtime.h>
#include <math.h>

#define EPSF 1e-9f

// ---------------------------------------------------------------------------
// Kernel 1: one block per batch element b (256 blocks x 1024 threads).
// Fused single pass over out_ids + trg_labels[1:-1]:
//   - per-(t,b) label dot product -> id NLL partials
//   - dist_r[b,:] accumulated in registers (4 cols/thread)
// Then per-b candidate-union dedup + Pm + Pb + KL, all in LDS/registers.
// Atomic partials: acc[0]=id_num, acc[1]=id_mask_cnt, acc[2]=kl_sum.
// ---------------------------------------------------------------------------
__global__ __launch_bounds__(1024) void e2e3_big(
    const float* __restrict__ selector_probs,   // [256,2,32] -> [256,64]
    const float* __restrict__ out_ids,          // [48,256,4096]
    const float* __restrict__ trg_labels,       // [50,256,4096]
    const int*   __restrict__ candi_ids,        // [256,64]
    const int*   __restrict__ routes,           // [256,4096]
    float* __restrict__ acc)
{
    const int b    = blockIdx.x;
    const int tid  = threadIdx.x;
    const int wave = tid >> 6;
    const int lane = tid & 63;
    const int v0   = tid << 2;                  // 4 columns per thread

    __shared__ float sdot[48][17];
    __shared__ float sls[48][17];
    __shared__ int   ids_s[64];
    __shared__ int   rep_s[64];
    __shared__ float valid_s[64];
    __shared__ float pmlog_s[64];
    __shared__ float agg_s[64];

    const size_t tstride = (size_t)256 * 4096;
    const float* outp = out_ids   + (size_t)b * 4096 + v0;
    const float* labp = trg_labels + tstride + (size_t)b * 4096 + v0; // row t+1

    float4 dist = make_float4(0.f, 0.f, 0.f, 0.f);

    for (int t = 0; t < 48; ++t) {
        const float4 o = *reinterpret_cast<const float4*>(outp + (size_t)t * tstride);
        const float4 l = *reinterpret_cast<const float4*>(labp + (size_t)t * tstride);
        dist.x += o.x; dist.y += o.y; dist.z += o.z; dist.w += o.w;
        float dot = o.x * l.x + o.y * l.y + o.z * l.z + o.w * l.w;
        float ls  = l.x + l.y + l.z + l.w;
        #pragma unroll
        for (int off = 32; off >= 1; off >>= 1) {
            dot += __shfl_down(dot, off, 64);
            ls  += __shfl_down(ls,  off, 64);
        }
        if (lane == 0) { sdot[t][wave] = dot; sls[t][wave] = ls; }
    }
    __syncthreads();

    // ---- id NLL partials: thread t<48 reduces the 16 wave partials ----
    float idnum = 0.f, idcnt = 0.f;
    if (tid < 48) {
        float d = 0.f, l = 0.f;
        #pragma unroll
        for (int w = 0; w < 16; ++w) { d += sdot[tid][w]; l += sls[tid][w]; }
        if (l > 0.5f) { idnum = -logf(fmaxf(d, EPSF)); idcnt = 1.f; }
    }
    if (wave == 0) {
        #pragma unroll
        for (int off = 32; off >= 1; off >>= 1) {
            idnum += __shfl_down(idnum, off, 64);
            idcnt += __shfl_down(idcnt, off, 64);
        }
        if (lane == 0) { atomicAdd(&acc[0], idnum); atomicAdd(&acc[1], idcnt); }
    }

    // ---- candidate-union dedup (first occurrence) ----
    if (tid < 64) ids_s[tid] = candi_ids[b * 64 + tid];
    __syncthreads();
    if (tid < 64) {
        const int my = ids_s[tid];
        int r = tid;
        for (int j = 0; j < 64; ++j) { if (ids_s[j] == my) { r = j; break; } }
        rep_s[tid]   = r;
        valid_s[tid] = (r == tid) ? 1.f : 0.f;
        agg_s[tid]   = 0.f;
    }
    __syncthreads();

    // ---- Pm: scatter selector probs onto union slots, normalize, take log ----
    if (tid < 64) {
        float pm = 0.f;
        for (int i = 0; i < 64; ++i)
            if (rep_s[i] == tid) pm += selector_probs[b * 64 + i];
        float tot = pm;
        #pragma unroll
        for (int off = 32; off >= 1; off >>= 1) tot += __shfl_xor(tot, off, 64);
        pm = pm / fmaxf(tot, EPSF);
        pmlog_s[tid] = logf(fmaxf(pm, EPSF));
    }
    __syncthreads();

    // ---- agg[u] = sum_v (routes[b,v]==ids[u]) * dist_r[b,v], valid slots only ----
    {
        const int4 rv = *reinterpret_cast<const int4*>(routes + (size_t)b * 4096 + v0);
        const int   rr[4] = {rv.x, rv.y, rv.z, rv.w};
        const float dv[4] = {dist.x, dist.y, dist.z, dist.w};
        for (int u = 0; u < 64; ++u) {
            if (valid_s[u] > 0.5f) {               // uniform across block
                const int idu = ids_s[u];          // LDS broadcast
                #pragma unroll
                for (int j = 0; j < 4; ++j)
                    if (rr[j] == idu) atomicAdd(&agg_s[u], dv[j]);
            }
        }
    }
    __syncthreads();

    // ---- Pb + KL over the 64 slots (wave 0) ----
    if (tid < 64) {
        const float va = valid_s[tid];
        const float a  = agg_s[tid];
        float s = a, uc = va;
        #pragma unroll
        for (int off = 32; off >= 1; off >>= 1) {
            s  += __shfl_xor(s,  off, 64);
            uc += __shfl_xor(uc, off, 64);
        }
        const float pb = (s > 0.f) ? (a / fmaxf(s, EPSF)) : (va / fmaxf(uc, 1.f));
        float term = 0.f;
        if (va > 0.5f) {
            const float pbc = fmaxf(pb, EPSF);
            term = pbc * (logf(pbc) - pmlog_s[tid]);
        }
        #pragma unroll
        for (int off = 32; off >= 1; off >>= 1) term += __shfl_down(term, off, 64);
        if (tid == 0) atomicAdd(&acc[2], term);
    }
}

// ---------------------------------------------------------------------------
// Kernel 2: all the small terms + final combine. Single block, 256 threads.
// ---------------------------------------------------------------------------
__global__ __launch_bounds__(256) void e2e3_small(
    const float* __restrict__ selector_probs,   // [256,64]
    const float* __restrict__ selector_onehot,  // [256,64]
    const float* __restrict__ out_rates,        // [48,256]
    const float* __restrict__ trg_rates,        // [50,256]
    const int*   __restrict__ trg_lengths,      // [256]
    const float* __restrict__ acc,              // [3]
    float* __restrict__ out)
{
    const int tid  = threadIdx.x;
    const int wave = tid >> 6;
    const int lane = tid & 63;

    float v_selnum = 0.f, v_selcnt = 0.f, v_ent = 0.f;
    float v_rate = 0.f, v_den = 0.f, v_smooth = 0.f;

    // selector NLL: 512 (b,j) groups of K=32
    for (int g = tid; g < 512; g += 256) {
        const float* pp = selector_probs  + g * 32;
        const float* oo = selector_onehot + g * 32;
        float p = 0.f, m = 0.f;
        #pragma unroll
        for (int k = 0; k < 32; ++k) { p += pp[k] * oo[k]; m += oo[k]; }
        if (m > 0.5f) { v_selnum += -logf(fmaxf(p, EPSF)); v_selcnt += 1.f; }
    }
    // entropy over selector_probs (raw, clamped)
    for (int i = tid; i < 256 * 64; i += 256) {
        const float p = fmaxf(selector_probs[i], EPSF);
        v_ent += -p * logf(p);
    }
    // rate L1: out_rates[t,b] vs trg_rates[t+1,b]
    for (int i = tid; i < 48 * 256; i += 256)
        v_rate += fabsf(out_rates[i] - trg_rates[i + 256]);
    // rate denominator: sum(trg_lengths - 2)
    for (int b2 = tid; b2 < 256; b2 += 256)
        v_den += (float)(trg_lengths[b2] - 2);
    // smoothness: |r[t+1]-r[t]| masked by t < max(len-3,0)
    for (int i = tid; i < 47 * 256; i += 256) {
        const int b2 = i & 255;
        const int t  = i >> 8;
        int eff = trg_lengths[b2] - 3; if (eff < 0) eff = 0;
        if (t < eff) v_smooth += fabsf(out_rates[i + 256] - out_rates[i]);
    }

    __shared__ float red[6][4];
    float vals[6] = {v_selnum, v_selcnt, v_ent, v_rate, v_den, v_smooth};
    #pragma unroll
    for (int k = 0; k < 6; ++k) {
        float v = vals[k];
        #pragma unroll
        for (int off = 32; off >= 1; off >>= 1) v += __shfl_down(v, off, 64);
        if (lane == 0) red[k][wave] = v;
    }
    __syncthreads();
    if (tid == 0) {
        float s[6];
        #pragma unroll
        for (int k = 0; k < 6; ++k) s[k] = red[k][0] + red[k][1] + red[k][2] + red[k][3];
        const float loss =
              s[0] / fmaxf(s[1], 1.f)                      // LAM_SEL * loss_sel
            + 10.f * acc[0] / fmaxf(acc[1], 1.f)           // loss_id
            + 5.f  * s[3]   / fmaxf(s[4], 1.f)             // loss_rate
            + 0.1f * acc[2] * (1.f / 256.f)                // loss_kl
            + 0.05f * 0.5f * s[2] * (1.f / 256.f)          // loss_entropy
            + 0.5f * s[5];                                 // loss_smooth
        out[0] = loss;
    }
}

extern "C" void kernel_launch(void* const* d_in, const int* in_sizes, int n_in,
                              void* d_out, int out_size, void* d_ws, size_t ws_size,
                              hipStream_t stream) {
    const float* selector_probs  = (const float*)d_in[1];
    const float* selector_onehot = (const float*)d_in[2];
    const float* out_ids         = (const float*)d_in[3];
    const float* out_rates       = (const float*)d_in[4];
    const float* trg_labels      = (const float*)d_in[5];
    const float* trg_rates       = (const float*)d_in[6];
    const int*   trg_lengths     = (const int*)d_in[7];
    const int*   candi_ids       = (const int*)d_in[8];
    const int*   routes          = (const int*)d_in[9];

    float* acc = (float*)d_ws;   // [0]=id_num [1]=id_cnt [2]=kl_sum
    hipMemsetAsync(acc, 0, 3 * sizeof(float), stream);

    e2e3_big<<<256, 1024, 0, stream>>>(selector_probs, out_ids, trg_labels,
                                       candi_ids, routes, acc);
    e2e3_small<<<1, 256, 0, stream>>>(selector_probs, selector_onehot,
                                      out_rates, trg_rates, trg_lengths,
                                      acc, (float*)d_out);
}